// Round 2
// baseline (354.177 us; speedup 1.0000x reference)
//
#include <hip/hip_runtime.h>
#include <hip/hip_bf16.h>

#define K_DIM 4096
#define N_DIM 4096
#define M_DIM 4096

#define BM 128
#define BN 128
#define BK 32

typedef __attribute__((ext_vector_type(8))) short bf16x8;   // 8 bf16 in 4 VGPRs
typedef __attribute__((ext_vector_type(4))) float f32x4;
typedef __attribute__((ext_vector_type(8))) unsigned short u16x8;

// ---------- fp32 -> bf16 (round-to-nearest-even) ----------
__device__ __forceinline__ unsigned short f2bf(float f) {
    union { float f; unsigned int u; } v; v.f = f;
    unsigned int u = v.u;
    return (unsigned short)((u + 0x7fffu + ((u >> 16) & 1u)) >> 16);
}

// ---------- fused convert: x and W in one launch ----------
__global__ void cvt2_f32_to_bf16(const float* __restrict__ x,
                                 const float* __restrict__ W,
                                 unsigned short* __restrict__ xb,
                                 unsigned short* __restrict__ wb,
                                 int blocks_each) {
    int b = blockIdx.x;
    const float* src = x;
    unsigned short* dst = xb;
    if (b >= blocks_each) { b -= blocks_each; src = W; dst = wb; }
    const int i = (b * 256 + threadIdx.x) * 8;
    float4 f0 = *(const float4*)(src + i);
    float4 f1 = *(const float4*)(src + i + 4);
    u16x8 o;
    o[0] = f2bf(f0.x); o[1] = f2bf(f0.y); o[2] = f2bf(f0.z); o[3] = f2bf(f0.w);
    o[4] = f2bf(f1.x); o[5] = f2bf(f1.y); o[6] = f2bf(f1.z); o[7] = f2bf(f1.w);
    *(u16x8*)(dst + i) = o;
}

// ---------- async global->LDS, 16B per lane (dest = uniform base + lane*16) ----------
__device__ __forceinline__ void gl_lds16(const void* g, void* l) {
    __builtin_amdgcn_global_load_lds(
        (const __attribute__((address_space(1))) void*)g,
        (__attribute__((address_space(3))) void*)l,
        16, 0, 0);
}

// ---------- GEMM: C[M,N] = A[M,K] * B[N,K]^T + bias[N] ----------
// LDS layout (per tile, per row r of BK=32 elems split into 4 chunks of 8):
//   global k-chunk q stored at slot (q ^ ((r>>1)&3))  -> every 8 consecutive
//   lanes of a ds_read_b128 hit all 32 banks (conflict-free; was 4-way).
// Double-buffered: prefetch tile k+1 issued AFTER the barrier, so the next
// barrier's vmcnt(0) drain waits on loads that aged a full compute phase.
template <bool BF16SRC>
__global__ __launch_bounds__(256) void gemm_bt(
    const void* __restrict__ Aptr, const void* __restrict__ Bptr,
    const float* __restrict__ bias, float* __restrict__ C) {

    __shared__ __align__(16) unsigned short As[2][BM * BK];  // 2 x 8 KB
    __shared__ __align__(16) unsigned short Bs[2][BN * BK];  // 2 x 8 KB

    const int tid  = threadIdx.x;
    const int wave = tid >> 6;
    const int lane = tid & 63;
    const int l16  = lane & 15;
    const int quad = lane >> 4;

    const int bm = blockIdx.y * BM;
    const int bn = blockIdx.x * BN;

    const int wm = (wave & 1) * 64;
    const int wn = (wave >> 1) * 64;

    // staging coords (bf16 path): lane writes LDS granule 16B*lane at wave base;
    // that granule is row (tid>>2), stored-slot (tid&3); source global chunk is
    // slot ^ swizzle(row), swizzle(row) = (row>>1)&3 = (tid>>3)&3.
    const int srow  = tid >> 2;                                // 0..63
    const int skq   = (((tid & 3) ^ ((tid >> 3) & 3))) << 3;   // global k offset
    const int wbase = wave << 9;                               // wave*512 elems

    f32x4 acc[4][4] = {};

    auto stage_bf16 = [&](int buf, int k0) {
        const unsigned short* A = (const unsigned short*)Aptr;
        const unsigned short* B = (const unsigned short*)Bptr;
        gl_lds16(&A[(size_t)(bm + srow) * K_DIM + k0 + skq],      &As[buf][wbase]);
        gl_lds16(&A[(size_t)(bm + 64 + srow) * K_DIM + k0 + skq], &As[buf][2048 + wbase]);
        gl_lds16(&B[(size_t)(bn + srow) * K_DIM + k0 + skq],      &Bs[buf][wbase]);
        gl_lds16(&B[(size_t)(bn + 64 + srow) * K_DIM + k0 + skq], &Bs[buf][2048 + wbase]);
    };

    auto stage_f32 = [&](int buf, int k0) {
        const float* A = (const float*)Aptr;
        const float* B = (const float*)Bptr;
        const int r  = tid >> 1;           // 0..127
        const int q0 = (tid & 1) << 1;     // chunk 0 or 2 (covers q0, q0+1)
        const int s  = (r >> 1) & 3;
        {
            const float* sp = &A[(size_t)(bm + r) * K_DIM + k0 + (q0 << 3)];
            float4 f0 = *(const float4*)(sp + 0);
            float4 f1 = *(const float4*)(sp + 4);
            float4 f2 = *(const float4*)(sp + 8);
            float4 f3 = *(const float4*)(sp + 12);
            u16x8 o0, o1;
            o0[0]=f2bf(f0.x); o0[1]=f2bf(f0.y); o0[2]=f2bf(f0.z); o0[3]=f2bf(f0.w);
            o0[4]=f2bf(f1.x); o0[5]=f2bf(f1.y); o0[6]=f2bf(f1.z); o0[7]=f2bf(f1.w);
            o1[0]=f2bf(f2.x); o1[1]=f2bf(f2.y); o1[2]=f2bf(f2.z); o1[3]=f2bf(f2.w);
            o1[4]=f2bf(f3.x); o1[5]=f2bf(f3.y); o1[6]=f2bf(f3.z); o1[7]=f2bf(f3.w);
            *(u16x8*)&As[buf][r * BK + ((q0 ^ s) << 3)]       = o0;
            *(u16x8*)&As[buf][r * BK + (((q0 + 1) ^ s) << 3)] = o1;
        }
        {
            const float* sp = &B[(size_t)(bn + r) * K_DIM + k0 + (q0 << 3)];
            float4 f0 = *(const float4*)(sp + 0);
            float4 f1 = *(const float4*)(sp + 4);
            float4 f2 = *(const float4*)(sp + 8);
            float4 f3 = *(const float4*)(sp + 12);
            u16x8 o0, o1;
            o0[0]=f2bf(f0.x); o0[1]=f2bf(f0.y); o0[2]=f2bf(f0.z); o0[3]=f2bf(f0.w);
            o0[4]=f2bf(f1.x); o0[5]=f2bf(f1.y); o0[6]=f2bf(f1.z); o0[7]=f2bf(f1.w);
            o1[0]=f2bf(f2.x); o1[1]=f2bf(f2.y); o1[2]=f2bf(f2.z); o1[3]=f2bf(f2.w);
            o1[4]=f2bf(f3.x); o1[5]=f2bf(f3.y); o1[6]=f2bf(f3.z); o1[7]=f2bf(f3.w);
            *(u16x8*)&Bs[buf][r * BK + ((q0 ^ s) << 3)]       = o0;
            *(u16x8*)&Bs[buf][r * BK + (((q0 + 1) ^ s) << 3)] = o1;
        }
    };

    if constexpr (BF16SRC) stage_bf16(0, 0); else stage_f32(0, 0);

    // read-side swizzle: for fragment rows r = (multiple of 16) + l16,
    // swizzle(r) = (r>>1)&3 reduces to (l16>>1)&3 — t-independent.
    const int sw   = (l16 >> 1) & 3;
    const int roff = ((quad ^ sw) << 3);

    for (int k0 = 0; k0 < K_DIM; k0 += BK) {
        const int buf = (k0 >> 5) & 1;
        __syncthreads();  // drains prefetch issued last iter; fences buf^1 reads

        if (k0 + BK < K_DIM) {
            if constexpr (BF16SRC) stage_bf16(buf ^ 1, k0 + BK);
            else stage_f32(buf ^ 1, k0 + BK);
        }

        const unsigned short* Ab = &As[buf][(wm + l16) * BK + roff];
        const unsigned short* Bb = &Bs[buf][(wn + l16) * BK + roff];
        bf16x8 af[4], bfv[4];
#pragma unroll
        for (int t = 0; t < 4; t++) af[t]  = *(const bf16x8*)&Ab[t * 16 * BK];
#pragma unroll
        for (int t = 0; t < 4; t++) bfv[t] = *(const bf16x8*)&Bb[t * 16 * BK];
#pragma unroll
        for (int i = 0; i < 4; i++)
#pragma unroll
            for (int j = 0; j < 4; j++)
                acc[i][j] = __builtin_amdgcn_mfma_f32_16x16x32_bf16(
                    af[i], bfv[j], acc[i][j], 0, 0, 0);
    }

    // epilogue: D[row=quad*4+r][col=l16] per 16x16 tile; fused bias
#pragma unroll
    for (int i = 0; i < 4; i++) {
        const int rbase = bm + wm + i * 16 + quad * 4;
#pragma unroll
        for (int j = 0; j < 4; j++) {
            const int col = bn + wn + j * 16 + l16;
            const float bv = bias[col];
#pragma unroll
            for (int r = 0; r < 4; r++)
                C[(size_t)(rbase + r) * N_DIM + col] = acc[i][j][r] + bv;
        }
    }
}

extern "C" void kernel_launch(void* const* d_in, const int* in_sizes, int n_in,
                              void* d_out, int out_size, void* d_ws, size_t ws_size,
                              hipStream_t stream) {
    const float* x = (const float*)d_in[0];   // [M, K]
    const float* W = (const float*)d_in[1];   // [N, K]
    const float* b = (const float*)d_in[2];   // [N]
    float* out = (float*)d_out;               // [M, N]

    const size_t elems = (size_t)M_DIM * K_DIM;               // == N*K here
    const size_t need  = 2 * elems * sizeof(unsigned short);  // 64 MB

    dim3 grid(N_DIM / BN, M_DIM / BM);
    dim3 block(256);

    if (ws_size >= need) {
        unsigned short* xb = (unsigned short*)d_ws;
        unsigned short* wb = xb + elems;
        const int blocks_each = (int)(elems / (256 * 8));     // 8192
        cvt2_f32_to_bf16<<<2 * blocks_each, 256, 0, stream>>>(x, W, xb, wb, blocks_each);
        gemm_bt<true><<<grid, block, 0, stream>>>(xb, wb, b, out);
    } else {
        gemm_bt<false><<<grid, block, 0, stream>>>(x, W, b, out);
    }
}